// Round 17
// baseline (93.029 us; speedup 1.0000x reference)
//
#include <hip/hip_runtime.h>
#include <hip/hip_bf16.h>
#include <stdint.h>

#define NB 64
#define NA 33600
#define NK 500
#define HW3 25600
#define HW4 6400
#define HW5 1600
#define OFF4 25600
#define OFF5 32000
#define NA4 8400
#define NSEG 33          // 33 blocks of 256 threads x 4 anchors per batch
#define NBIN 256
#define LCAP 1024
#define MROWS 512        // padded rows per batch in mask

typedef unsigned short u16;
typedef unsigned int u32;
typedef unsigned long long u64;

__device__ __forceinline__ float sigf(float x) { return 1.0f / (1.0f + expf(-x)); }

__device__ __forceinline__ u32 f2key(float f) {
  u32 u = __float_as_uint(f);
  return (u & 0x80000000u) ? ~u : (u | 0x80000000u);
}
__device__ __forceinline__ float key2f(u32 k) {
  u32 u = (k & 0x80000000u) ? (k ^ 0x80000000u) : ~k;
  return __uint_as_float(u);
}
__device__ __forceinline__ int bin_of(float s) {
  int b = (int)(s * 256.0f);
  return b > 255 ? 255 : b;   // monotone nondecreasing in s
}
__device__ __forceinline__ u32 mkkey(float o, float c0, float c1) {
  float so = sigf(o);
  float s = fmaxf(so * sigf(c0), so * sigf(c1));
  float masked = (s > 0.3f) ? s : -1.0f;
  return f2key(masked);
}
__device__ __forceinline__ u64 uniform64(u64 v) {
  u32 lo = (u32)__builtin_amdgcn_readfirstlane((int)(u32)v);
  u32 hi = (u32)__builtin_amdgcn_readfirstlane((int)(u32)(v >> 32));
  return ((u64)hi << 32) | lo;
}

// ---- K1: score -> keys + per-block partial 256-bin hist (full-chip) ---------
// NO in-kernel cross-block coherence (R13 lesson). Kernel boundary provides it.
__global__ __launch_bounds__(256) void k_score(
    const float* __restrict__ cls3, const float* __restrict__ obj3,
    const float* __restrict__ cls4, const float* __restrict__ obj4,
    const float* __restrict__ cls5, const float* __restrict__ obj5,
    uint4* __restrict__ keys4, u16* __restrict__ ghist_part, u32* __restrict__ cnt)
{
  int seg = blockIdx.x, b = blockIdx.y, tid = threadIdx.x;
  int i4 = seg * 256 + tid;
  __shared__ u32 hist[NBIN];
  hist[tid] = 0;
  if (seg == 0 && tid == 0) cnt[b] = 0;
  __syncthreads();

  if (i4 < NA4) {
    const float* cls; const float* obj; int p4, HW;
    if (i4 < 6400)      { cls = cls3; obj = obj3; p4 = i4;        HW = HW3; }
    else if (i4 < 8000) { cls = cls4; obj = obj4; p4 = i4 - 6400; HW = HW4; }
    else                { cls = cls5; obj = obj5; p4 = i4 - 8000; HW = HW5; }
    float4 o  = reinterpret_cast<const float4*>(obj + (size_t)b * HW)[p4];
    float4 c0 = reinterpret_cast<const float4*>(cls + (size_t)(b * 2) * HW)[p4];
    float4 c1 = reinterpret_cast<const float4*>(cls + (size_t)(b * 2 + 1) * HW)[p4];
    uint4 kv;
    kv.x = mkkey(o.x, c0.x, c1.x);
    kv.y = mkkey(o.y, c0.y, c1.y);
    kv.z = mkkey(o.z, c0.z, c1.z);
    kv.w = mkkey(o.w, c0.w, c1.w);
    keys4[(size_t)b * NA4 + i4] = kv;
    u32 ks[4] = {kv.x, kv.y, kv.z, kv.w};
#pragma unroll
    for (int c = 0; c < 4; ++c) {
      float s = key2f(ks[c]);
      if (s > 0.3f) atomicAdd(&hist[bin_of(s)], 1u);
    }
  }
  __syncthreads();
  if (tid < 128) {
    u32 pk = (hist[2 * tid] & 0xFFFFu) | (hist[2 * tid + 1] << 16);
    reinterpret_cast<u32*>(ghist_part + ((size_t)(b * NSEG + seg) * NBIN))[tid] = pk;
  }
}

// ---- K2: collect candidates; pivot computed IN-BLOCK (redundant, L2-hot) ----
__global__ __launch_bounds__(256) void k_collect(
    const u32* __restrict__ keys, const u16* __restrict__ ghist_part,
    u64* __restrict__ cand, u32* __restrict__ cnt)
{
  int seg = blockIdx.x, b = blockIdx.y, tid = threadIdx.x;
  __shared__ u32 part[NBIN];
  __shared__ int sh_p;
  __shared__ u64 loc[1024];
  __shared__ u32 lcnt;
  __shared__ u32 gbase;

  u32 sum = 0;
  for (int s2 = 0; s2 < NSEG; ++s2)
    sum += ghist_part[(size_t)(b * NSEG + s2) * NBIN + tid];
  part[tid] = sum;
  if (tid == 0) lcnt = 0;
  __syncthreads();
  for (int off = 1; off < NBIN; off <<= 1) {
    u32 add = (tid + off < NBIN) ? part[tid + off] : 0u;
    __syncthreads();
    part[tid] += add;
    __syncthreads();
  }
  if (tid == 0 && part[0] < NK) sh_p = NBIN;   // <500 valid: collect nothing
  u32 S = part[tid];
  u32 Snext = (tid == NBIN - 1) ? 0u : part[tid + 1];
  if (S >= NK && Snext < NK) sh_p = tid;
  __syncthreads();
  int p = sh_p;

  int i4 = seg * 256 + tid;
  if (i4 < NA4) {
    uint4 kv = reinterpret_cast<const uint4*>(keys + (size_t)b * NA)[i4];
    u32 ks[4] = {kv.x, kv.y, kv.z, kv.w};
#pragma unroll
    for (int c = 0; c < 4; ++c) {
      float s = key2f(ks[c]);
      if (s > 0.3f && bin_of(s) >= p) {
        u32 slot = atomicAdd(&lcnt, 1u);
        loc[slot] = ((u64)ks[c] << 16) | (u32)(0xFFFF - (i4 * 4 + c));
      }
    }
  }
  __syncthreads();
  if (tid == 0) gbase = atomicAdd(&cnt[b], lcnt);
  __syncthreads();
  u32 n = lcnt, gb = gbase;
  for (u32 i = tid; i < n; i += 256) {
    u32 slot = gb + i;
    if (slot < LCAP) cand[(size_t)b * LCAP + slot] = loc[i];
    // cnt > LCAP or < NK -> k_sortdec takes exact fallback
  }
}

// ---- K3: counting-rank (distinct keys, barrier-free) + decode ---------------
__global__ __launch_bounds__(512) void k_sortdec(
    const u32* __restrict__ keys, const u64* __restrict__ gcand,
    const u32* __restrict__ cnt,
    const float* __restrict__ cls3, const float* __restrict__ obj3, const float* __restrict__ reg3,
    const float* __restrict__ cls4, const float* __restrict__ obj4, const float* __restrict__ reg4,
    const float* __restrict__ cls5, const float* __restrict__ obj5, const float* __restrict__ reg5,
    float* __restrict__ top_score,
    float4* __restrict__ boxes, float4* __restrict__ boxesoff,
    float* __restrict__ out_labels)
{
  int b = blockIdx.x, tid = threadIdx.x;
  __shared__ u64 cand[LCAP];
  __shared__ int idx_lds[NK];
  __shared__ float score_lds[NK];
  __shared__ u32 hist[256];
  __shared__ u32 part[256];
  __shared__ u32 sh_R;
  __shared__ int sh_digit;
  __shared__ u32 sh_cnt;

  u32 n = cnt[b];
  bool fail = (n < (u32)NK) || (n > LCAP);
  const u32* kb = keys + (size_t)b * NA;

  if (!fail) {
    for (int i = tid; i < (int)n; i += 512)
      cand[i] = gcand[(size_t)b * LCAP + i];
    __syncthreads();
    // counting-rank: keys distinct -> unique ranks; n >= NK guaranteed here,
    // so every rank < NK is written exactly once. Broadcast LDS reads, no
    // barriers (vs 55 barriered bitonic stages).
    for (int t = tid; t < (int)n; t += 512) {
      u64 kk = cand[t];
      int rank = 0;
      for (int j = 0; j < (int)n; ++j) rank += (cand[j] > kk) ? 1 : 0;
      if (rank < NK) {
        idx_lds[rank] = 0xFFFF - (int)(kk & 0xFFFFull);
        score_lds[rank] = key2f((u32)(kk >> 16));
      }
    }
  } else {
    // exact 48-bit radix select over keys (rare path)
    u64 prefix = 0, prefmask = 0;
    u32 R = NK;
    for (int pass = 0; pass < 6; ++pass) {
      int shift = 40 - 8 * pass;
      if (tid < 256) part[tid] = 0;
      __syncthreads();
      for (int i = tid; i < NA; i += 512) {
        u64 k48 = ((u64)kb[i] << 16) | (u32)(0xFFFF - i);
        if ((k48 & prefmask) == prefix)
          atomicAdd(&part[(u32)(k48 >> shift) & 255u], 1u);
      }
      __syncthreads();
      if (tid < 256) hist[tid] = part[tid];
      __syncthreads();
      for (int off = 1; off < 256; off <<= 1) {
        u32 add = 0;
        if (tid < 256 && tid + off < 256) add = hist[tid + off];
        __syncthreads();
        if (tid < 256) hist[tid] += add;
        __syncthreads();
      }
      if (tid < 256) {
        u32 s = hist[tid];
        u32 snext = (tid == 255) ? 0u : hist[tid + 1];
        if (s >= R && snext < R) { sh_digit = tid; sh_R = R - snext; }
      }
      __syncthreads();
      prefix |= ((u64)sh_digit) << shift;
      R = sh_R;
      prefmask |= 0xFFull << shift;
      __syncthreads();
    }
    if (tid == 0) sh_cnt = 0;
    if (tid < NK) { idx_lds[tid] = 0; score_lds[tid] = -1.0f; }
    __syncthreads();
    for (int i = tid; i < NA; i += 512) {
      u64 k48 = ((u64)kb[i] << 16) | (u32)(0xFFFF - i);
      if (k48 >= prefix) {
        u32 slot = atomicAdd(&sh_cnt, 1u);
        if (slot < 512) cand[slot] = k48;
      }
    }
    __syncthreads();
    int m = (sh_cnt < (u32)NK) ? (int)sh_cnt : NK;
    for (int t = tid; t < m; t += 512) {
      u64 k = cand[t];
      int rank = 0;
      for (int j = 0; j < m; ++j) rank += (cand[j] > k) ? 1 : 0;
      if (rank < NK) {
        idx_lds[rank] = 0xFFFF - (int)(k & 0xFFFFull);
        score_lds[rank] = key2f((u32)(k >> 16));
      }
    }
  }
  __syncthreads();

  if (tid < NK) {
    int a = idx_lds[tid];
    const float *cls, *obj, *reg; int pos, HW, x, y; float stride;
    if (a < OFF4) {
      cls = cls3; obj = obj3; reg = reg3; pos = a; HW = HW3; stride = 8.0f;
      y = pos / 160; x = pos - y * 160;
    } else if (a < OFF5) {
      cls = cls4; obj = obj4; reg = reg4; pos = a - OFF4; HW = HW4; stride = 16.0f;
      y = pos / 80; x = pos - y * 80;
    } else {
      cls = cls5; obj = obj5; reg = reg5; pos = a - OFF5; HW = HW5; stride = 32.0f;
      y = pos / 40; x = pos - y * 40;
    }
    float dx = reg[(b * 4 + 0) * HW + pos];
    float dy = reg[(b * 4 + 1) * HW + pos];
    float dw = reg[(b * 4 + 2) * HW + pos];
    float dh = reg[(b * 4 + 3) * HW + pos];
    float cx = ((float)x + sigf(dx)) * stride;
    float cy = ((float)y + sigf(dy)) * stride;
    float w = expf(dw) * stride;
    float h = expf(dh) * stride;
    float x1 = cx - w * 0.5f, y1 = cy - h * 0.5f;
    float x2 = cx + w * 0.5f, y2 = cy + h * 0.5f;
    float so = sigf(obj[b * HW + pos]);
    float s0 = so * sigf(cls[(b * 2) * HW + pos]);
    float s1 = so * sigf(cls[(b * 2 + 1) * HW + pos]);
    int label = (s1 > s0) ? 1 : 0;
    float off = (float)label * 10000.0f;
    int t = b * NK + tid;
    boxes[t]    = make_float4(x1, y1, x2, y2);
    boxesoff[t] = make_float4(x1 + off, y1 + off, x2 + off, y2 + off);
    out_labels[t] = (float)label;
    top_score[t] = score_lds[tid];
  }
}

// ---- K4: suppression bit-matrix, UPPER TRIANGLE ONLY (w >= i>>6) ------------
// k_nms's relaxation reads only words w >= c (plus himask on the diagonal),
// so the lower triangle is dead work — skip it (~43% fewer inner loops).
__global__ __launch_bounds__(256) void k_iou(
    const float4* __restrict__ boxesoff, u64* __restrict__ mask)
{
  int t = blockIdx.x * 256 + threadIdx.x;
  if (t >= NB * NK * 8) return;
  int w = t & 7;
  int bi = t >> 3;
  int b = bi / NK;
  int i = bi - b * NK;
  if (w < (i >> 6)) return;            // lower triangle: never read by k_nms
  float4 A = boxesoff[bi];
  float areaA = (A.z - A.x) * (A.w - A.y);
  const float4* base = boxesoff + b * NK;
  int j0 = w * 64;
  int jmax = (NK - j0 < 64) ? (NK - j0) : 64;
  u64 bits = 0;
  for (int jj = 0; jj < jmax; ++jj) {
    float4 Bx = base[j0 + jj];
    float areaB = (Bx.z - Bx.x) * (Bx.w - Bx.y);
    float ix1 = fmaxf(A.x, Bx.x);
    float iy1 = fmaxf(A.y, Bx.y);
    float ix2 = fminf(A.z, Bx.z);
    float iy2 = fminf(A.w, Bx.w);
    float iw = fmaxf(ix2 - ix1, 0.0f);
    float ih = fmaxf(iy2 - iy1, 0.0f);
    float inter = iw * ih;
    float uni = areaA + areaB - inter;
    float iou = inter / (uni + 1e-7f);
    bits |= ((u64)(iou >= 0.5f)) << jj;
  }
  mask[(size_t)b * (MROWS * 8) + (size_t)i * 8 + w] = bits;
}

// ---- K5: greedy NMS via parallel fixed-point relaxation (validated) ---------
// K_{t+1}[i] = valid[i] & !OR_{j<i}(K_t[j] & M[j][i]).  Unique fixed point ==
// sequential greedy (triangular induction); cap 600 > 501 guarantees exact.
// Loads only the upper-triangle words (w >= c) — the rest are never used.
__global__ __launch_bounds__(64) void k_nms(
    const u64* __restrict__ mask, const float* __restrict__ top_score,
    const float4* __restrict__ boxes,
    float* __restrict__ out_boxes, float* __restrict__ out_scores,
    float* __restrict__ out_keep)
{
  int b = blockIdx.x;
  int lane = threadIdx.x;
  const u64* mb = mask + (size_t)b * (MROWS * 8);

  u64 rw[8][8];   // only [c][w>=c] initialized/used (unrolled -> SROA-dead rest)
#pragma unroll
  for (int c = 0; c < 8; ++c) {
    const u64* rp = mb + (size_t)(c * 64 + lane) * 8;
#pragma unroll
    for (int w = 0; w < 8; ++w)
      if (w >= c) rw[c][w] = rp[w];
  }

  u64 validw[8];
#pragma unroll
  for (int c = 0; c < 8; ++c) {
    int r = c * 64 + lane;
    float s = (r < NK) ? top_score[b * NK + r] : -1.0f;
    validw[c] = __ballot(s > 0.3f);
  }

  u64 himask = (lane == 63) ? 0ull : (~0ull << (lane + 1));
  u64 k[8];
#pragma unroll
  for (int w = 0; w < 8; ++w) k[w] = validw[w];

  for (int it = 0; it < 600; ++it) {
    u64 acc[8] = {0, 0, 0, 0, 0, 0, 0, 0};
#pragma unroll
    for (int c = 0; c < 8; ++c) {
      u64 msel = 0ull - ((k[c] >> lane) & 1ull);
      acc[c] |= rw[c][c] & himask & msel;
#pragma unroll
      for (int w = c + 1; w < 8; ++w) acc[w] |= rw[c][w] & msel;
    }
#pragma unroll
    for (int off = 1; off < 64; off <<= 1) {
#pragma unroll
      for (int w = 0; w < 8; ++w)
        acc[w] |= (u64)__shfl_xor((unsigned long long)acc[w], off, 64);
    }
    bool conv = true;
#pragma unroll
    for (int w = 0; w < 8; ++w) {
      u64 nk = validw[w] & ~uniform64(acc[w]);
      conv = conv && (nk == k[w]);
      k[w] = nk;
    }
    if (conv) break;    // wave-uniform branch
  }

#pragma unroll
  for (int c = 0; c < 8; ++c) {
    int r = c * 64 + lane;
    if (r < NK) {
      int kp = (int)((k[c] >> lane) & 1ull);
      float4 bx = boxes[b * NK + r];
      float s = top_score[b * NK + r];
      float4 ob;
      ob.x = kp ? bx.x : 0.0f;
      ob.y = kp ? bx.y : 0.0f;
      ob.z = kp ? bx.z : 0.0f;
      ob.w = kp ? bx.w : 0.0f;
      reinterpret_cast<float4*>(out_boxes)[b * NK + r] = ob;
      out_scores[b * NK + r] = kp ? s : 0.0f;
      out_keep[b * NK + r]   = kp ? 1.0f : 0.0f;
    }
  }
}

// ---------------- launcher ---------------------------------------------------
extern "C" void kernel_launch(void* const* d_in, const int* in_sizes, int n_in,
                              void* d_out, int out_size, void* d_ws, size_t ws_size,
                              hipStream_t stream) {
  const float* cls3 = (const float*)d_in[0];
  const float* reg3 = (const float*)d_in[1];
  const float* obj3 = (const float*)d_in[2];
  const float* cls4 = (const float*)d_in[3];
  const float* reg4 = (const float*)d_in[4];
  const float* obj4 = (const float*)d_in[5];
  const float* cls5 = (const float*)d_in[6];
  const float* reg5 = (const float*)d_in[7];
  const float* obj5 = (const float*)d_in[8];

  char* ws = (char*)d_ws;
  u32*    keys      = (u32*)   (ws + 0);           //  8,601,600
  u16*    ghist     = (u16*)   (ws + 8601600);     //  1,081,344
  u32*    cnt       = (u32*)   (ws + 9682944);     //        256
  u64*    cand      = (u64*)   (ws + 9683200);     //    524,288
  float*  top_score = (float*) (ws + 10207488);    //    128,000
  float4* boxes     = (float4*)(ws + 10335488);    //    512,000
  float4* boxesoff  = (float4*)(ws + 10847488);    //    512,000
  u64*    mask      = (u64*)   (ws + 11359488);    //  2,097,152  (end ~13.5 MB)

  float* out        = (float*)d_out;
  float* out_boxes  = out;
  float* out_scores = out + 128000;
  float* out_labels = out + 160000;
  float* out_keep   = out + 192000;

  dim3 gfull(NSEG, NB);
  k_score<<<gfull, 256, 0, stream>>>(cls3, obj3, cls4, obj4, cls5, obj5,
                                     (uint4*)keys, ghist, cnt);
  k_collect<<<gfull, 256, 0, stream>>>(keys, ghist, cand, cnt);
  k_sortdec<<<NB, 512, 0, stream>>>(keys, cand, cnt,
      cls3, obj3, reg3, cls4, obj4, reg4, cls5, obj5, reg5,
      top_score, boxes, boxesoff, out_labels);
  k_iou<<<(NB * NK * 8 + 255) / 256, 256, 0, stream>>>(boxesoff, mask);
  k_nms<<<NB, 64, 0, stream>>>(mask, top_score, boxes, out_boxes, out_scores, out_keep);
}

// Round 18
// 88.792 us; speedup vs baseline: 1.0477x; 1.0477x over previous
//
#include <hip/hip_runtime.h>
#include <hip/hip_bf16.h>
#include <stdint.h>

#define NB 64
#define NA 33600
#define NK 500
#define HW3 25600
#define HW4 6400
#define HW5 1600
#define OFF4 25600
#define OFF5 32000
#define NA4 8400
#define NSEG 33          // 33 blocks of 256 threads x 4 anchors per batch
#define NBIN 256
#define LCAP 1024
#define MROWS 512        // padded rows per batch in mask

typedef unsigned short u16;
typedef unsigned int u32;
typedef unsigned long long u64;

__device__ __forceinline__ float sigf(float x) { return 1.0f / (1.0f + expf(-x)); }

__device__ __forceinline__ u32 f2key(float f) {
  u32 u = __float_as_uint(f);
  return (u & 0x80000000u) ? ~u : (u | 0x80000000u);
}
__device__ __forceinline__ float key2f(u32 k) {
  u32 u = (k & 0x80000000u) ? (k ^ 0x80000000u) : ~k;
  return __uint_as_float(u);
}
__device__ __forceinline__ int bin_of(float s) {
  int b = (int)(s * 256.0f);
  return b > 255 ? 255 : b;   // monotone nondecreasing in s
}
__device__ __forceinline__ u64 uniform64(u64 v) {
  u32 lo = (u32)__builtin_amdgcn_readfirstlane((int)(u32)v);
  u32 hi = (u32)__builtin_amdgcn_readfirstlane((int)(u32)(v >> 32));
  return ((u64)hi << 32) | lo;
}
// masked score for one anchor-quad; identical FP sequence everywhere
__device__ __forceinline__ float mscore(float o, float c0, float c1) {
  float so = sigf(o);
  float s = fmaxf(so * sigf(c0), so * sigf(c1));
  return s;   // caller tests s > 0.3f
}

// ---- K1: per-block partial 256-bin hist of scores (full-chip, read-only) ----
// NO keys write: inputs become L3-resident; later kernels recompute scores.
// NO in-kernel cross-block coherence (R13 lesson).
__global__ __launch_bounds__(256) void k_hist(
    const float* __restrict__ cls3, const float* __restrict__ obj3,
    const float* __restrict__ cls4, const float* __restrict__ obj4,
    const float* __restrict__ cls5, const float* __restrict__ obj5,
    u16* __restrict__ ghist_part, u32* __restrict__ cnt)
{
  int seg = blockIdx.x, b = blockIdx.y, tid = threadIdx.x;
  int i4 = seg * 256 + tid;
  __shared__ u32 hist[NBIN];
  hist[tid] = 0;
  if (seg == 0 && tid == 0) cnt[b] = 0;   // single writer, no fence needed
  __syncthreads();

  if (i4 < NA4) {
    const float* cls; const float* obj; int p4, HW;
    if (i4 < 6400)      { cls = cls3; obj = obj3; p4 = i4;        HW = HW3; }
    else if (i4 < 8000) { cls = cls4; obj = obj4; p4 = i4 - 6400; HW = HW4; }
    else                { cls = cls5; obj = obj5; p4 = i4 - 8000; HW = HW5; }
    float4 o  = reinterpret_cast<const float4*>(obj + (size_t)b * HW)[p4];
    float4 c0 = reinterpret_cast<const float4*>(cls + (size_t)(b * 2) * HW)[p4];
    float4 c1 = reinterpret_cast<const float4*>(cls + (size_t)(b * 2 + 1) * HW)[p4];
    float s;
    s = mscore(o.x, c0.x, c1.x); if (s > 0.3f) atomicAdd(&hist[bin_of(s)], 1u);
    s = mscore(o.y, c0.y, c1.y); if (s > 0.3f) atomicAdd(&hist[bin_of(s)], 1u);
    s = mscore(o.z, c0.z, c1.z); if (s > 0.3f) atomicAdd(&hist[bin_of(s)], 1u);
    s = mscore(o.w, c0.w, c1.w); if (s > 0.3f) atomicAdd(&hist[bin_of(s)], 1u);
  }
  __syncthreads();
  if (tid < 128) {
    u32 pk = (hist[2 * tid] & 0xFFFFu) | (hist[2 * tid + 1] << 16);
    reinterpret_cast<u32*>(ghist_part + ((size_t)(b * NSEG + seg) * NBIN))[tid] = pk;
  }
}

// ---- K2: collect candidates; pivot IN-BLOCK; scores recomputed (L3-hot) -----
__global__ __launch_bounds__(256) void k_collect(
    const float* __restrict__ cls3, const float* __restrict__ obj3,
    const float* __restrict__ cls4, const float* __restrict__ obj4,
    const float* __restrict__ cls5, const float* __restrict__ obj5,
    const u16* __restrict__ ghist_part,
    u64* __restrict__ cand, u32* __restrict__ cnt)
{
  int seg = blockIdx.x, b = blockIdx.y, tid = threadIdx.x;
  __shared__ u32 part[NBIN];
  __shared__ int sh_p;
  __shared__ u64 loc[1024];
  __shared__ u32 lcnt;
  __shared__ u32 gbase;

  // redundant pivot: reduce this batch's 33 partial hists (16.9 KB, L2-hot)
  u32 sum = 0;
  for (int s2 = 0; s2 < NSEG; ++s2)
    sum += ghist_part[(size_t)(b * NSEG + s2) * NBIN + tid];
  part[tid] = sum;
  if (tid == 0) lcnt = 0;
  __syncthreads();
  for (int off = 1; off < NBIN; off <<= 1) {
    u32 add = (tid + off < NBIN) ? part[tid + off] : 0u;
    __syncthreads();
    part[tid] += add;
    __syncthreads();
  }
  if (tid == 0 && part[0] < NK) sh_p = NBIN;   // <500 valid: collect nothing
  u32 S = part[tid];
  u32 Snext = (tid == NBIN - 1) ? 0u : part[tid + 1];
  if (S >= NK && Snext < NK) sh_p = tid;
  __syncthreads();
  int p = sh_p;

  int i4 = seg * 256 + tid;
  if (i4 < NA4) {
    const float* cls; const float* obj; int p4, HW;
    if (i4 < 6400)      { cls = cls3; obj = obj3; p4 = i4;        HW = HW3; }
    else if (i4 < 8000) { cls = cls4; obj = obj4; p4 = i4 - 6400; HW = HW4; }
    else                { cls = cls5; obj = obj5; p4 = i4 - 8000; HW = HW5; }
    float4 o  = reinterpret_cast<const float4*>(obj + (size_t)b * HW)[p4];
    float4 c0 = reinterpret_cast<const float4*>(cls + (size_t)(b * 2) * HW)[p4];
    float4 c1 = reinterpret_cast<const float4*>(cls + (size_t)(b * 2 + 1) * HW)[p4];
    float sv[4];
    sv[0] = mscore(o.x, c0.x, c1.x);
    sv[1] = mscore(o.y, c0.y, c1.y);
    sv[2] = mscore(o.z, c0.z, c1.z);
    sv[3] = mscore(o.w, c0.w, c1.w);
#pragma unroll
    for (int c = 0; c < 4; ++c) {
      float s = sv[c];
      if (s > 0.3f && bin_of(s) >= p) {
        u32 slot = atomicAdd(&lcnt, 1u);   // <=1024 anchors/block, no overflow
        loc[slot] = ((u64)f2key(s) << 16) | (u32)(0xFFFF - (i4 * 4 + c));
      }
    }
  }
  __syncthreads();
  if (tid == 0) gbase = atomicAdd(&cnt[b], lcnt);
  __syncthreads();
  u32 n = lcnt, gb = gbase;
  for (u32 i = tid; i < n; i += 256) {
    u32 slot = gb + i;
    if (slot < LCAP) cand[(size_t)b * LCAP + slot] = loc[i];
    // cnt > LCAP or < NK -> k_sortdec takes exact fallback
  }
}

// ---- helper: masked score of a single anchor (scalar, fallback path) --------
__device__ __forceinline__ float anchor_score(
    int b, int a,
    const float* cls3, const float* obj3,
    const float* cls4, const float* obj4,
    const float* cls5, const float* obj5)
{
  const float* cls; const float* obj; int pos, HW;
  if (a < OFF4)      { cls = cls3; obj = obj3; pos = a;        HW = HW3; }
  else if (a < OFF5) { cls = cls4; obj = obj4; pos = a - OFF4; HW = HW4; }
  else               { cls = cls5; obj = obj5; pos = a - OFF5; HW = HW5; }
  return mscore(obj[b * HW + pos], cls[(b * 2) * HW + pos], cls[(b * 2 + 1) * HW + pos]);
}

// ---- K3: bitonic sort (512 thr) + decode; exact fallback recomputes keys ----
__global__ __launch_bounds__(512) void k_sortdec(
    const u64* __restrict__ gcand, const u32* __restrict__ cnt,
    const float* __restrict__ cls3, const float* __restrict__ obj3, const float* __restrict__ reg3,
    const float* __restrict__ cls4, const float* __restrict__ obj4, const float* __restrict__ reg4,
    const float* __restrict__ cls5, const float* __restrict__ obj5, const float* __restrict__ reg5,
    float* __restrict__ top_score,
    float4* __restrict__ boxes, float4* __restrict__ boxesoff,
    float* __restrict__ out_labels)
{
  int b = blockIdx.x, tid = threadIdx.x;
  __shared__ u64 cand[LCAP];
  __shared__ int idx_lds[NK];
  __shared__ float score_lds[NK];
  __shared__ u32 hist[256];
  __shared__ u32 part[256];
  __shared__ u32 sh_R;
  __shared__ int sh_digit;
  __shared__ u32 sh_cnt;

  u32 n = cnt[b];
  bool fail = (n < (u32)NK) || (n > LCAP);

  if (!fail) {
    for (int i = tid; i < LCAP; i += 512)
      cand[i] = (i < (int)n) ? gcand[(size_t)b * LCAP + i] : 0ull;
    for (int k = 2; k <= LCAP; k <<= 1) {
      for (int j = k >> 1; j > 0; j >>= 1) {
        __syncthreads();
        // 512 threads == 512 compare-exchanges per stage, no idle waves
        int i = ((tid & ~(j - 1)) << 1) | (tid & (j - 1));
        int ixj = i | j;
        u64 a = cand[i], c2 = cand[ixj];
        bool dir = ((i & k) == 0);
        if ((a < c2) == dir) { cand[i] = c2; cand[ixj] = a; }
      }
    }
    __syncthreads();
    if (tid < NK) {
      u64 kk = cand[tid];
      idx_lds[tid] = 0xFFFF - (int)(kk & 0xFFFFull);
      score_lds[tid] = key2f((u32)(kk >> 16));
    }
  } else {
    // exact 48-bit radix select; keys recomputed from (L3-hot) inputs.
    // Never taken for this data; correctness path only.
    u64 prefix = 0, prefmask = 0;
    u32 R = NK;
    for (int pass = 0; pass < 6; ++pass) {
      int shift = 40 - 8 * pass;
      if (tid < 256) part[tid] = 0;
      __syncthreads();
      for (int i = tid; i < NA; i += 512) {
        float s = anchor_score(b, i, cls3, obj3, cls4, obj4, cls5, obj5);
        float masked = (s > 0.3f) ? s : -1.0f;
        u64 k48 = ((u64)f2key(masked) << 16) | (u32)(0xFFFF - i);
        if ((k48 & prefmask) == prefix)
          atomicAdd(&part[(u32)(k48 >> shift) & 255u], 1u);
      }
      __syncthreads();
      if (tid < 256) hist[tid] = part[tid];
      __syncthreads();
      for (int off = 1; off < 256; off <<= 1) {
        u32 add = 0;
        if (tid < 256 && tid + off < 256) add = hist[tid + off];
        __syncthreads();
        if (tid < 256) hist[tid] += add;
        __syncthreads();
      }
      if (tid < 256) {
        u32 s = hist[tid];
        u32 snext = (tid == 255) ? 0u : hist[tid + 1];
        if (s >= R && snext < R) { sh_digit = tid; sh_R = R - snext; }
      }
      __syncthreads();
      prefix |= ((u64)sh_digit) << shift;
      R = sh_R;
      prefmask |= 0xFFull << shift;
      __syncthreads();
    }
    if (tid == 0) sh_cnt = 0;
    if (tid < NK) { idx_lds[tid] = 0; score_lds[tid] = -1.0f; }
    __syncthreads();
    for (int i = tid; i < NA; i += 512) {
      float s = anchor_score(b, i, cls3, obj3, cls4, obj4, cls5, obj5);
      float masked = (s > 0.3f) ? s : -1.0f;
      u64 k48 = ((u64)f2key(masked) << 16) | (u32)(0xFFFF - i);
      if (k48 >= prefix) {
        u32 slot = atomicAdd(&sh_cnt, 1u);
        if (slot < 512) cand[slot] = k48;
      }
    }
    __syncthreads();
    int m = (sh_cnt < (u32)NK) ? (int)sh_cnt : NK;
    for (int t = tid; t < m; t += 512) {
      u64 k = cand[t];
      int rank = 0;
      for (int j = 0; j < m; ++j) rank += (cand[j] > k) ? 1 : 0;
      if (rank < NK) {
        idx_lds[rank] = 0xFFFF - (int)(k & 0xFFFFull);
        score_lds[rank] = key2f((u32)(k >> 16));
      }
    }
  }
  __syncthreads();

  if (tid < NK) {
    int a = idx_lds[tid];
    const float *cls, *obj, *reg; int pos, HW, x, y; float stride;
    if (a < OFF4) {
      cls = cls3; obj = obj3; reg = reg3; pos = a; HW = HW3; stride = 8.0f;
      y = pos / 160; x = pos - y * 160;
    } else if (a < OFF5) {
      cls = cls4; obj = obj4; reg = reg4; pos = a - OFF4; HW = HW4; stride = 16.0f;
      y = pos / 80; x = pos - y * 80;
    } else {
      cls = cls5; obj = obj5; reg = reg5; pos = a - OFF5; HW = HW5; stride = 32.0f;
      y = pos / 40; x = pos - y * 40;
    }
    float dx = reg[(b * 4 + 0) * HW + pos];
    float dy = reg[(b * 4 + 1) * HW + pos];
    float dw = reg[(b * 4 + 2) * HW + pos];
    float dh = reg[(b * 4 + 3) * HW + pos];
    float cx = ((float)x + sigf(dx)) * stride;
    float cy = ((float)y + sigf(dy)) * stride;
    float w = expf(dw) * stride;
    float h = expf(dh) * stride;
    float x1 = cx - w * 0.5f, y1 = cy - h * 0.5f;
    float x2 = cx + w * 0.5f, y2 = cy + h * 0.5f;
    float so = sigf(obj[b * HW + pos]);
    float s0 = so * sigf(cls[(b * 2) * HW + pos]);
    float s1 = so * sigf(cls[(b * 2 + 1) * HW + pos]);
    int label = (s1 > s0) ? 1 : 0;
    float off = (float)label * 10000.0f;
    int t = b * NK + tid;
    boxes[t]    = make_float4(x1, y1, x2, y2);
    boxesoff[t] = make_float4(x1 + off, y1 + off, x2 + off, y2 + off);
    out_labels[t] = (float)label;
    top_score[t] = score_lds[tid];
  }
}

// ---- K4: suppression bit-matrix (iou >= 0.5), padded layout (full-chip) -----
__global__ __launch_bounds__(256) void k_iou(
    const float4* __restrict__ boxesoff, u64* __restrict__ mask)
{
  int t = blockIdx.x * 256 + threadIdx.x;
  if (t >= NB * NK * 8) return;
  int w = t & 7;
  int bi = t >> 3;
  int b = bi / NK;
  int i = bi - b * NK;
  float4 A = boxesoff[bi];
  float areaA = (A.z - A.x) * (A.w - A.y);
  const float4* base = boxesoff + b * NK;
  int j0 = w * 64;
  int jmax = (NK - j0 < 64) ? (NK - j0) : 64;
  u64 bits = 0;
  for (int jj = 0; jj < jmax; ++jj) {
    float4 Bx = base[j0 + jj];
    float areaB = (Bx.z - Bx.x) * (Bx.w - Bx.y);
    float ix1 = fmaxf(A.x, Bx.x);
    float iy1 = fmaxf(A.y, Bx.y);
    float ix2 = fminf(A.z, Bx.z);
    float iy2 = fminf(A.w, Bx.w);
    float iw = fmaxf(ix2 - ix1, 0.0f);
    float ih = fmaxf(iy2 - iy1, 0.0f);
    float inter = iw * ih;
    float uni = areaA + areaB - inter;
    float iou = inter / (uni + 1e-7f);
    bits |= ((u64)(iou >= 0.5f)) << jj;
  }
  mask[(size_t)b * (MROWS * 8) + (size_t)i * 8 + w] = bits;
}

// ---- K5: greedy NMS via parallel fixed-point relaxation (validated) ---------
// K_{t+1}[i] = valid[i] & !OR_{j<i}(K_t[j] & M[j][i]).  Unique fixed point ==
// sequential greedy (triangular induction); cap 600 > 501 guarantees exact.
__global__ __launch_bounds__(64) void k_nms(
    const u64* __restrict__ mask, const float* __restrict__ top_score,
    const float4* __restrict__ boxes,
    float* __restrict__ out_boxes, float* __restrict__ out_scores,
    float* __restrict__ out_keep)
{
  int b = blockIdx.x;
  int lane = threadIdx.x;
  const u64* mb = mask + (size_t)b * (MROWS * 8);

  u64 rw[8][8];
#pragma unroll
  for (int c = 0; c < 8; ++c) {
    const ulonglong2* rp =
        reinterpret_cast<const ulonglong2*>(mb + (size_t)(c * 64 + lane) * 8);
#pragma unroll
    for (int q = 0; q < 4; ++q) {
      ulonglong2 v = rp[q];
      rw[c][2 * q] = v.x;
      rw[c][2 * q + 1] = v.y;
    }
  }

  u64 validw[8];
#pragma unroll
  for (int c = 0; c < 8; ++c) {
    int r = c * 64 + lane;
    float s = (r < NK) ? top_score[b * NK + r] : -1.0f;
    validw[c] = __ballot(s > 0.3f);
  }

  u64 himask = (lane == 63) ? 0ull : (~0ull << (lane + 1));
  u64 k[8];
#pragma unroll
  for (int w = 0; w < 8; ++w) k[w] = validw[w];

  for (int it = 0; it < 600; ++it) {
    u64 acc[8] = {0, 0, 0, 0, 0, 0, 0, 0};
#pragma unroll
    for (int c = 0; c < 8; ++c) {
      u64 msel = 0ull - ((k[c] >> lane) & 1ull);
      acc[c] |= rw[c][c] & himask & msel;
#pragma unroll
      for (int w = c + 1; w < 8; ++w) acc[w] |= rw[c][w] & msel;
    }
#pragma unroll
    for (int off = 1; off < 64; off <<= 1) {
#pragma unroll
      for (int w = 0; w < 8; ++w)
        acc[w] |= (u64)__shfl_xor((unsigned long long)acc[w], off, 64);
    }
    bool conv = true;
#pragma unroll
    for (int w = 0; w < 8; ++w) {
      u64 nk = validw[w] & ~uniform64(acc[w]);
      conv = conv && (nk == k[w]);
      k[w] = nk;
    }
    if (conv) break;    // wave-uniform branch
  }

#pragma unroll
  for (int c = 0; c < 8; ++c) {
    int r = c * 64 + lane;
    if (r < NK) {
      int kp = (int)((k[c] >> lane) & 1ull);
      float4 bx = boxes[b * NK + r];
      float s = top_score[b * NK + r];
      float4 ob;
      ob.x = kp ? bx.x : 0.0f;
      ob.y = kp ? bx.y : 0.0f;
      ob.z = kp ? bx.z : 0.0f;
      ob.w = kp ? bx.w : 0.0f;
      reinterpret_cast<float4*>(out_boxes)[b * NK + r] = ob;
      out_scores[b * NK + r] = kp ? s : 0.0f;
      out_keep[b * NK + r]   = kp ? 1.0f : 0.0f;
    }
  }
}

// ---------------- launcher ---------------------------------------------------
extern "C" void kernel_launch(void* const* d_in, const int* in_sizes, int n_in,
                              void* d_out, int out_size, void* d_ws, size_t ws_size,
                              hipStream_t stream) {
  const float* cls3 = (const float*)d_in[0];
  const float* reg3 = (const float*)d_in[1];
  const float* obj3 = (const float*)d_in[2];
  const float* cls4 = (const float*)d_in[3];
  const float* reg4 = (const float*)d_in[4];
  const float* obj4 = (const float*)d_in[5];
  const float* cls5 = (const float*)d_in[6];
  const float* reg5 = (const float*)d_in[7];
  const float* obj5 = (const float*)d_in[8];

  char* ws = (char*)d_ws;
  u16*    ghist     = (u16*)   (ws + 0);           //  1,081,344
  u32*    cnt       = (u32*)   (ws + 1081344);     //        256
  u64*    cand      = (u64*)   (ws + 1081600);     //    524,288
  float*  top_score = (float*) (ws + 1605888);     //    128,000
  float4* boxes     = (float4*)(ws + 1733888);     //    512,000
  float4* boxesoff  = (float4*)(ws + 2245888);     //    512,000
  u64*    mask      = (u64*)   (ws + 2757888);     //  2,097,152  (end ~4.9 MB)

  float* out        = (float*)d_out;
  float* out_boxes  = out;
  float* out_scores = out + 128000;
  float* out_labels = out + 160000;
  float* out_keep   = out + 192000;

  dim3 gfull(NSEG, NB);
  k_hist<<<gfull, 256, 0, stream>>>(cls3, obj3, cls4, obj4, cls5, obj5,
                                    ghist, cnt);
  k_collect<<<gfull, 256, 0, stream>>>(cls3, obj3, cls4, obj4, cls5, obj5,
                                       ghist, cand, cnt);
  k_sortdec<<<NB, 512, 0, stream>>>(cand, cnt,
      cls3, obj3, reg3, cls4, obj4, reg4, cls5, obj5, reg5,
      top_score, boxes, boxesoff, out_labels);
  k_iou<<<(NB * NK * 8 + 255) / 256, 256, 0, stream>>>(boxesoff, mask);
  k_nms<<<NB, 64, 0, stream>>>(mask, top_score, boxes, out_boxes, out_scores, out_keep);
}